// Round 3
// baseline (231.296 us; speedup 1.0000x reference)
//
#include <hip/hip_runtime.h>
#include <hip/hip_bf16.h>

#define IN_FEATS 602
#define N_HIDDEN 256
#define N_CLASSES 41
#define N_SRC0 292864
#define N_DST0 11264
#define N_DST1 1024
#define FAN0 25
#define FAN1 10
#define KPAD 1216            // 1204 rounded up to multiple of 64

typedef __attribute__((ext_vector_type(4))) float f32x4;
typedef __attribute__((ext_vector_type(8))) short bf16x8;   // 8 bf16 = 4 VGPRs

// round-to-nearest-even f32 -> bf16, packed pair
static __device__ __forceinline__ unsigned pack_bf16x2(float lo, float hi) {
    unsigned a = __float_as_uint(lo);
    unsigned b = __float_as_uint(hi);
    a = (a + 0x7fffu + ((a >> 16) & 1u)) >> 16;
    b = (b + 0x7fffu + ((b >> 16) & 1u)) >> 16;
    return (a & 0xffffu) | (b << 16);
}

// ---------------------------------------------------------------------------
// Kernel 1: build A[d] = [ bf16(x[d]) (602) | bf16(mean_25 x[idx]) (602) | 0 pad (12) ]
// One wave per dst (4 dsts/block). float2 vector loads (x rows are 8-B aligned),
// 25 independent loads in flight per lane, packed uint bf16x2 stores.
// ---------------------------------------------------------------------------
__global__ __launch_bounds__(256) void agg0_kernel(
    const float* __restrict__ x,
    const int* __restrict__ idx,
    __hip_bfloat16* __restrict__ A)
{
    const int wave = threadIdx.x >> 6;
    const int lane = threadIdx.x & 63;
    const int d = blockIdx.x * 4 + wave;

    __shared__ int sidx[4][FAN0];
    if (lane < FAN0) sidx[wave][lane] = idx[d * FAN0 + lane];
    __syncthreads();

    unsigned* Aself  = (unsigned*)(A + (size_t)d * KPAD);            // pairs, 602 floats = 301 pairs
    const float* xself = x + (size_t)d * IN_FEATS;

    // zero the 12 pad cols (elements 1204..1215 = uint slots 602..607)
    if (lane < 6) Aself[602 + lane] = 0u;

    #pragma unroll
    for (int p = 0; p < 5; ++p) {
        const int f2 = p * 64 + lane;          // float2 index, 0..300
        if (f2 > 300) break;
        const int f = f2 * 2;
        float sx = 0.f, sy = 0.f;
        #pragma unroll
        for (int n = 0; n < FAN0; ++n) {
            const float2 v = *(const float2*)&x[(size_t)sidx[wave][n] * IN_FEATS + f];
            sx += v.x; sy += v.y;
        }
        const float2 s = *(const float2*)&xself[f];
        Aself[f2] = pack_bf16x2(s.x, s.y);
        // neigh half starts at element 602 -> byte 1204 -> uint-aligned
        ((unsigned*)((__hip_bfloat16*)Aself + IN_FEATS))[f2] =
            pack_bf16x2(sx * (1.0f / FAN0), sy * (1.0f / FAN0));
    }
}

// ---------------------------------------------------------------------------
// Kernel 2: Wt[n][k] = bf16( k<602 ? Wself0[k][n] : k<1204 ? Wneigh0[k-602][n] : 0 )
// Wt is [N_HIDDEN][KPAD] bf16 (B-operand pre-transposed, K-major per row).
// ---------------------------------------------------------------------------
__global__ __launch_bounds__(256) void wprep_kernel(
    const float* __restrict__ Ws,
    const float* __restrict__ Wn,
    __hip_bfloat16* __restrict__ Wt)
{
    __shared__ float tile[32][33];
    const int k0 = blockIdx.x * 32, n0 = blockIdx.y * 32;
    const int tx = threadIdx.x & 31, ty = threadIdx.x >> 5;   // 32 x 8

    #pragma unroll
    for (int i = 0; i < 4; ++i) {
        const int k = k0 + ty + i * 8;
        const int n = n0 + tx;
        float v = 0.f;
        if (k < IN_FEATS)            v = Ws[(size_t)k * N_HIDDEN + n];
        else if (k < 2 * IN_FEATS)   v = Wn[(size_t)(k - IN_FEATS) * N_HIDDEN + n];
        tile[ty + i * 8][tx] = v;
    }
    __syncthreads();
    #pragma unroll
    for (int i = 0; i < 4; ++i) {
        const int n = n0 + ty + i * 8;
        const int k = k0 + tx;
        Wt[(size_t)n * KPAD + k] = __float2bfloat16(tile[tx][ty + i * 8]);
    }
}

// ---------------------------------------------------------------------------
// Kernel 3: h = relu(A @ Wt^T + b0) via bf16 MFMA, f32 accumulate.
// M=11264, N=256, K=1216. 64x64 tile, BK=64 (8 MFMA per barrier pair),
// 4 waves of 32x32. LDS rows padded to 72 bf16 (144 B) -> even bank spread.
// ---------------------------------------------------------------------------
#define BKK 64
#define LDSW 72

__global__ __launch_bounds__(256) void gemm0_mfma(
    const __hip_bfloat16* __restrict__ A,     // [N_DST0][KPAD]
    const __hip_bfloat16* __restrict__ Wt,    // [N_HIDDEN][KPAD]
    const float* __restrict__ bias,           // [256]
    float* __restrict__ h)                    // [N_DST0][256]
{
    __shared__ __hip_bfloat16 As[64 * LDSW];
    __shared__ __hip_bfloat16 Bs[64 * LDSW];

    const int tid  = threadIdx.x;
    const int lane = tid & 63;
    const int wave = tid >> 6;
    const int wm = wave >> 1, wn = wave & 1;    // 2x2 waves of 32x32
    const int g = lane >> 4, r = lane & 15;
    const int m0 = blockIdx.y * 64, n0 = blockIdx.x * 64;

    const int srow = tid >> 2;                  // 0..63
    const int sc   = (tid & 3) * 16;            // 0,16,32,48 (bf16 elems; 2 chunks each)

    const size_t a_off = (size_t)(m0 + srow) * KPAD + sc;
    const size_t b_off = (size_t)(n0 + srow) * KPAD + sc;

    f32x4 acc[2][2] = {};

    for (int k0 = 0; k0 < KPAD; k0 += BKK) {
        *(float4*)&As[srow * LDSW + sc]     = *(const float4*)&A[a_off + k0];
        *(float4*)&As[srow * LDSW + sc + 8] = *(const float4*)&A[a_off + k0 + 8];
        *(float4*)&Bs[srow * LDSW + sc]     = *(const float4*)&Wt[b_off + k0];
        *(float4*)&Bs[srow * LDSW + sc + 8] = *(const float4*)&Wt[b_off + k0 + 8];
        __syncthreads();

        #pragma unroll
        for (int kh = 0; kh < 2; ++kh) {
            const bf16x8 af0 = *(const bf16x8*)&As[(wm * 32 +      r) * LDSW + kh * 32 + g * 8];
            const bf16x8 af1 = *(const bf16x8*)&As[(wm * 32 + 16 + r) * LDSW + kh * 32 + g * 8];
            const bf16x8 bf0 = *(const bf16x8*)&Bs[(wn * 32 +      r) * LDSW + kh * 32 + g * 8];
            const bf16x8 bf1 = *(const bf16x8*)&Bs[(wn * 32 + 16 + r) * LDSW + kh * 32 + g * 8];

            acc[0][0] = __builtin_amdgcn_mfma_f32_16x16x32_bf16(af0, bf0, acc[0][0], 0, 0, 0);
            acc[0][1] = __builtin_amdgcn_mfma_f32_16x16x32_bf16(af0, bf1, acc[0][1], 0, 0, 0);
            acc[1][0] = __builtin_amdgcn_mfma_f32_16x16x32_bf16(af1, bf0, acc[1][0], 0, 0, 0);
            acc[1][1] = __builtin_amdgcn_mfma_f32_16x16x32_bf16(af1, bf1, acc[1][1], 0, 0, 0);
        }
        __syncthreads();
    }

    // C/D layout (m89-verified): col = lane&15, row = (lane>>4)*4 + j
    #pragma unroll
    for (int mh = 0; mh < 2; ++mh)
        #pragma unroll
        for (int nh = 0; nh < 2; ++nh) {
            const int col = n0 + wn * 32 + nh * 16 + r;
            const float bv = bias[col];
            #pragma unroll
            for (int j = 0; j < 4; ++j) {
                const int row = m0 + wm * 32 + mh * 16 + g * 4 + j;
                const float v = acc[mh][nh][j] + bv;
                h[(size_t)row * N_HIDDEN + col] = fmaxf(v, 0.f);
            }
        }
}

// ---------------------------------------------------------------------------
// Kernel 4 (fused agg1 + layer1):
// out[d] = h[d] @ Wself1 + (mean_10 h[idx1]) @ Wneigh1 + b1     (f32)
// ---------------------------------------------------------------------------
__global__ __launch_bounds__(64) void tail_kernel(
    const float* __restrict__ h,
    const int* __restrict__ idx1,
    const float* __restrict__ Ws,     // [256][41]
    const float* __restrict__ Wn,     // [256][41]
    const float* __restrict__ b,      // [41]
    float* __restrict__ out)          // [1024][41]
{
    const int d = blockIdx.x;
    __shared__ float hd[N_HIDDEN];
    __shared__ float hn[N_HIDDEN];
    __shared__ int sidx[FAN1];
    if (threadIdx.x < FAN1) sidx[threadIdx.x] = idx1[d * FAN1 + threadIdx.x];
    __syncthreads();

    for (int k = threadIdx.x; k < N_HIDDEN; k += 64) {
        hd[k] = h[(size_t)d * N_HIDDEN + k];
        float a = 0.f;
        #pragma unroll
        for (int i = 0; i < FAN1; ++i)
            a += h[(size_t)sidx[i] * N_HIDDEN + k];
        hn[k] = a * (1.0f / FAN1);
    }
    __syncthreads();

    if (threadIdx.x < N_CLASSES) {
        const int n = threadIdx.x;
        float a0 = b[n], a1 = 0.f, a2 = 0.f, a3 = 0.f;
        #pragma unroll 4
        for (int k = 0; k < N_HIDDEN; k += 4) {
            a0 += hd[k + 0] * Ws[(k + 0) * N_CLASSES + n] + hn[k + 0] * Wn[(k + 0) * N_CLASSES + n];
            a1 += hd[k + 1] * Ws[(k + 1) * N_CLASSES + n] + hn[k + 1] * Wn[(k + 1) * N_CLASSES + n];
            a2 += hd[k + 2] * Ws[(k + 2) * N_CLASSES + n] + hn[k + 2] * Wn[(k + 2) * N_CLASSES + n];
            a3 += hd[k + 3] * Ws[(k + 3) * N_CLASSES + n] + hn[k + 3] * Wn[(k + 3) * N_CLASSES + n];
        }
        out[(size_t)d * N_CLASSES + n] = a0 + a1 + a2 + a3;
    }
}

// ---------------------------------------------------------------------------
extern "C" void kernel_launch(void* const* d_in, const int* in_sizes, int n_in,
                              void* d_out, int out_size, void* d_ws, size_t ws_size,
                              hipStream_t stream) {
    const float* x       = (const float*)d_in[0];
    const float* Wself0  = (const float*)d_in[1];
    const float* Wneigh0 = (const float*)d_in[2];
    const float* b0      = (const float*)d_in[3];
    const float* Wself1  = (const float*)d_in[4];
    const float* Wneigh1 = (const float*)d_in[5];
    const float* b1      = (const float*)d_in[6];
    const int*   idx0    = (const int*)d_in[7];
    const int*   idx1    = (const int*)d_in[8];
    float* out = (float*)d_out;

    // ws layout: A bf16 [11264*1216] | Wt bf16 [256*1216] | h f32 [11264*256]
    __hip_bfloat16* Abf = (__hip_bfloat16*)d_ws;
    __hip_bfloat16* Wt  = Abf + (size_t)N_DST0 * KPAD;
    float*          h   = (float*)(Wt + (size_t)N_HIDDEN * KPAD);

    wprep_kernel<<<dim3(KPAD / 32, N_HIDDEN / 32), 256, 0, stream>>>(Wself0, Wneigh0, Wt);
    agg0_kernel<<<N_DST0 / 4, 256, 0, stream>>>(x, idx0, Abf);
    gemm0_mfma<<<dim3(N_HIDDEN / 64, N_DST0 / 64), 256, 0, stream>>>(Abf, Wt, b0, h);
    tail_kernel<<<N_DST1, 64, 0, stream>>>(h, idx1, Wself1, Wneigh1, b1, out);
}